// Round 3
// baseline (1281.461 us; speedup 1.0000x reference)
//
#include <hip/hip_runtime.h>

// NeuralODE: B=1024, D=64, F=8, H=256, 196 substeps x 6 dopri5 stages.
// R12: 4 blocks/CU + lean MFMA. 1024 blocks x 256 threads, 1 row/block,
// __launch_bounds__(256,4) (VGPR<=128 -> 4 waves/SIMD from 4 indep blocks).
// R11 post-mortem: co-resident-block hiding confirmed (1626->1200us,
// MfmaUtil 5->43%). Stage=2450cyc; per SIMD: MFMA 1050cyc, VALU 1000cyc,
// rest exposed latency. R12 levers:
//  - W1-lo MFMA term DROPPED (GEMM1 24->12 MFMAs, wave total 32->20):
//    fp16 rounding of W1 adds ~7e-4 RMS to y (~3.5e-4 in h), same order as
//    the existing h-fp16 floor; predict absmax ~0.02-0.04 vs 0.105 thresh.
//    Also frees 48 VGPRs (b1l) for the 128-reg/4-wave budget.
//  - 1 row/block: all row-scaled issue (tanh x4, combine x1, z/h publish,
//    u-interp 48 slots) halves again; M=16 tile padding rows zeroed once.
//    Matrix pipe/SIMD: 4 waves x 20 x ~16.5cyc = 1320cyc/stage, VALU
//    ~500-700 -> stage floor ~1500-1800cyc (was 2450).
// Numerics: W1-hi only (prescaled 2*log2e), W2-hi only, fp32 state+combine,
// tanh = 1 - 2*rcp(exp2(y)+1).
// MFMA layouts (HW-verified R7/R8): A[m=l&15][k=(l>>4)*8+j],
//   B[k=(l>>4)*8+j][n=l&15], D[row=(l>>4)*4+reg][col=l&15].
// A-frag LDS planes [k>>3][m][k&7], stride 144 halves (288B).

typedef _Float16 half8 __attribute__((ext_vector_type(8)));
typedef float f32x4 __attribute__((ext_vector_type(4)));

#define MFMA16(a, b, c) __builtin_amdgcn_mfma_f32_16x16x32_f16((a), (b), (c), 0, 0, 0)

__global__ __launch_bounds__(256, 4)
void node_kernel(const float* __restrict__ x0,
                 const float* __restrict__ t_eval,
                 const float* __restrict__ t_u,
                 const float* __restrict__ u_batch,
                 const float* __restrict__ W1,
                 const float* __restrict__ b1,
                 const float* __restrict__ W2,
                 const float* __restrict__ b2,
                 float* __restrict__ out)
{
    __shared__ __align__(16) _Float16 zAh[12 * 144];   // z hi, K=96 (72+pad)
    __shared__ __align__(16) _Float16 hAh[32 * 144];   // h hi, K=256
    __shared__ __align__(16) float ush[6][8];          // interp u per stage

    const int tid = threadIdx.x;
    const int wv  = tid >> 6;        // wave 0..3
    const int l   = tid & 63;
    const int lm  = l & 15;
    const int lq  = l >> 4;
    const int blk = blockIdx.x;

    const float C2L = 2.8853900817779268f;   // 2*log2(e)

    // --- zero ALL of zAh/hAh once: padding rows/planes stay 0 forever ---
    for (int i = tid; i < (12 * 144) / 2; i += 256) ((uint32_t*)zAh)[i] = 0u;
    for (int i = tid; i < (32 * 144) / 2; i += 256) ((uint32_t*)hAh)[i] = 0u;

    // --- GEMM1 B-frags: wave owns N-tiles wv*4+t, hi only, prescaled ---
    half8 b1h[4][3];
    float b1b[4];
#pragma unroll
    for (int t = 0; t < 4; ++t) {
        const int n1 = (wv * 4 + t) * 16 + lm;
        b1b[t] = b1[n1] * C2L;
#pragma unroll
        for (int c = 0; c < 3; ++c) {
#pragma unroll
            for (int j = 0; j < 8; ++j) {
                const int k = c * 32 + lq * 8 + j;
                b1h[t][c][j] = (_Float16)((k < 72) ? W1[k * 256 + n1] * C2L : 0.0f);
            }
        }
    }

    // --- GEMM2 B-frags: wave owns N-tile wv, FULL K=256, hi only ---
    const int n2 = wv * 16 + lm;
    half8 b2h[8];
#pragma unroll
    for (int cc = 0; cc < 8; ++cc) {
#pragma unroll
        for (int j = 0; j < 8; ++j) {
            const int k = cc * 32 + lq * 8 + j;
            b2h[cc][j] = (_Float16)W2[k * 64 + n2];
        }
    }
    const float b2b = b2[n2];

    // --- ODE state: 1 row (tile row 0 <-> lq==0, reg 0). All lanes carry
    //     copies; only lq==0 lanes publish. ---
    float xr = x0[blk * 64 + n2];
    float kfr[5];
    if (lq == 0) out[blk * 3200 + n2] = xr;      // t_eval[0]
    __syncthreads();   // zero-init visible

#pragma unroll 1
    for (int step = 0; step < 196; ++step) {
        const int n = step >> 2;
        const int m = step & 3;
        const float te0 = t_eval[n];
        const float dtc = t_eval[n + 1] - te0;
        const float t   = te0 + dtc * (0.25f * (float)m);
        const float dt  = dtc * 0.25f;

        // --- u prefetch+interp: 48 slots (6 stages x 8 feats) ---
        if (tid < 48) {
            const int s = tid >> 3;
            const int f = tid & 7;
            float cs;
            switch (s) {
                case 0: cs = 0.0f; break;
                case 1: cs = 1.0f / 5.0f; break;
                case 2: cs = 3.0f / 10.0f; break;
                case 3: cs = 4.0f / 5.0f; break;
                case 4: cs = 8.0f / 9.0f; break;
                default: cs = 1.0f; break;
            }
            const float tsv = t + dt * cs;
            int iu = (int)(tsv * 127.0f);       // == searchsorted-1
            iu = iu < 0 ? 0 : (iu > 126 ? 126 : iu);
            const float ta = t_u[iu];
            const float tb = t_u[iu + 1];
            const float wt = (tsv - ta) / (tb - ta);
            const float* ub = &u_batch[blk * 1024 + iu * 8 + f];
            const float u0v = ub[0];
            const float u1v = ub[8];
            ush[s][f] = fmaf(wt, u1v - u0v, u0v);
        }
        __syncthreads();   // B0: ush ready

#pragma unroll
        for (int s = 0; s < 6; ++s) {
            // --- z x-part, row 0 (combine in all lanes, lq==0 writes) ---
            float zv;
            if (s == 0)      zv = xr;
            else if (s == 1) zv = fmaf(dt, kfr[0] * (1.0f/5.0f), xr);
            else if (s == 2) zv = fmaf(dt, fmaf(3.0f/40.0f, kfr[0], (9.0f/40.0f)*kfr[1]), xr);
            else if (s == 3) zv = fmaf(dt, (44.0f/45.0f)*kfr[0] + (-56.0f/15.0f)*kfr[1]
                                          + (32.0f/9.0f)*kfr[2], xr);
            else if (s == 4) zv = fmaf(dt, (19372.0f/6561.0f)*kfr[0] + (-25360.0f/2187.0f)*kfr[1]
                                          + (64448.0f/6561.0f)*kfr[2] + (-212.0f/729.0f)*kfr[3], xr);
            else             zv = fmaf(dt, (9017.0f/3168.0f)*kfr[0] + (-355.0f/33.0f)*kfr[1]
                                          + (46732.0f/5247.0f)*kfr[2] + (49.0f/176.0f)*kfr[3]
                                          + (-5103.0f/18656.0f)*kfr[4], xr);
            if (lq == 0)
                zAh[(n2 >> 3) * 144 + (n2 & 7)] = (_Float16)zv;
            // --- wave 1, lanes 0-3: z u-part row 0 (plane 8), packed ---
            if (wv == 1 && l < 4) {
                const int jj = l * 2;
                const _Float16 u0h = (_Float16)ush[s][jj];
                const _Float16 u1h = (_Float16)ush[s][jj + 1];
                uint32_t pk = (uint32_t)*(const uint16_t*)&u0h
                            | ((uint32_t)*(const uint16_t*)&u1h << 16);
                *(uint32_t*)&zAh[8 * 144 + jj] = pk;
            }
            __syncthreads();   // B1: z ready

            // --- GEMM1: 3 A-reads, 4 N-tiles, hi only, 12 MFMAs ---
            half8 az[3];
#pragma unroll
            for (int c = 0; c < 3; ++c)
                az[c] = *(const half8*)&zAh[(c * 4 + lq) * 144 + lm * 8];
#pragma unroll
            for (int t = 0; t < 4; ++t) {
                f32x4 aHH = {0.f, 0.f, 0.f, 0.f};
#pragma unroll
                for (int c = 0; c < 3; ++c)
                    aHH = MFMA16(az[c], b1h[t][c], aHH);
                const int kqb = (wv * 4 + t) * 2 + (lm >> 3);   // h-col>>3 plane
                // tanh only on row 0 (reg 0; valid in lq==0 lanes)
                const float y = aHH[0] + b1b[t];                 // 2log2e*(zW1+b1)
                const float e = __builtin_amdgcn_exp2f(y);
                const float hv = fmaf(-2.0f, __builtin_amdgcn_rcpf(e + 1.0f), 1.0f);
                if (lq == 0)
                    hAh[kqb * 144 + (lm & 7)] = (_Float16)hv;
            }
            __syncthreads();   // B2: h ready

            // --- GEMM2: full K=256, hi only, 8 MFMAs in 2 dep-chains of 4 ---
            f32x4 aP = {0.f, 0.f, 0.f, 0.f};
            f32x4 aR = {0.f, 0.f, 0.f, 0.f};
#pragma unroll
            for (int cc = 0; cc < 8; cc += 2) {
                const half8 ah0 = *(const half8*)&hAh[((cc    ) * 4 + lq) * 144 + lm * 8];
                const half8 ah1 = *(const half8*)&hAh[((cc + 1) * 4 + lq) * 144 + lm * 8];
                aP = MFMA16(ah0, b2h[cc    ], aP);
                aR = MFMA16(ah1, b2h[cc + 1], aR);
            }
            if (s < 5) {
                kfr[s] = (aP[0] + aR[0]) + b2b;
            } else {
                const float k6 = (aP[0] + aR[0]) + b2b;
                xr = fmaf(dt, (35.0f/384.0f)*kfr[0] + (500.0f/1113.0f)*kfr[2]
                             + (125.0f/192.0f)*kfr[3] + (-2187.0f/6784.0f)*kfr[4]
                             + (11.0f/84.0f)*k6, xr);
            }
        }

        // --- output every 4th substep ---
        if (m == 3 && lq == 0)
            out[blk * 3200 + (n + 1) * 64 + n2] = xr;
    }
}

extern "C" void kernel_launch(void* const* d_in, const int* in_sizes, int n_in,
                              void* d_out, int out_size, void* d_ws, size_t ws_size,
                              hipStream_t stream) {
    const float* x0      = (const float*)d_in[0];
    const float* t_eval  = (const float*)d_in[1];
    const float* t_u     = (const float*)d_in[2];
    const float* u_batch = (const float*)d_in[3];
    const float* W1      = (const float*)d_in[4];
    const float* b1      = (const float*)d_in[5];
    const float* W2      = (const float*)d_in[6];
    const float* b2      = (const float*)d_in[7];
    float* out = (float*)d_out;

    node_kernel<<<dim3(1024), dim3(256), 0, stream>>>(
        x0, t_eval, t_u, u_batch, W1, b1, W2, b2, out);
}